// Round 8
// baseline (1026.776 us; speedup 1.0000x reference)
//
#include <hip/hip_runtime.h>
#include <math.h>

#define MDIM 4096
#define NDIM 4096
#define DDIM 256
#define N_ITER 30

#define TWO_KAPPA 14.426950408889634
#define CLCONST  (-12.0 - TWO_KAPPA)

typedef __attribute__((ext_vector_type(8))) short bf16x8;
typedef __attribute__((ext_vector_type(4))) float f32x4;

__device__ __forceinline__ unsigned encf(float f) {
  unsigned u = __float_as_uint(f);
  return (u & 0x80000000u) ? ~u : (u | 0x80000000u);
}
__device__ __forceinline__ float decf(unsigned u) {
  return __uint_as_float((u & 0x80000000u) ? (u ^ 0x80000000u) : ~u);
}

#define AL_RLX(p)      __hip_atomic_load((p), __ATOMIC_RELAXED, __HIP_MEMORY_SCOPE_AGENT)
#define AS_RLX(p, v)   __hip_atomic_store((p), (v), __ATOMIC_RELAXED, __HIP_MEMORY_SCOPE_AGENT)
#define AADD_RLX(p, v) __hip_atomic_fetch_add((p), (v), __ATOMIC_RELAXED, __HIP_MEMORY_SCOPE_AGENT)
#define AMAX_RLX(p, v) __hip_atomic_fetch_max((p), (v), __ATOMIC_RELAXED, __HIP_MEMORY_SCOPE_AGENT)

// ---------- norms: xx[i], yy[j], Sxx ----------
__global__ void norms_kernel(const float* __restrict__ x, const float* __restrict__ y,
                             float* __restrict__ xx, float* __restrict__ yy,
                             float* __restrict__ Sxx) {
  int wid = threadIdx.x >> 6, lane = threadIdx.x & 63;
  int row = blockIdx.x * 4 + wid;
  const float* src = (row < MDIM) ? x : y;
  int r = (row < MDIM) ? row : row - MDIM;
  const float4* p = (const float4*)(src + (size_t)r * DDIM);
  float4 v = p[lane];
  float s = v.x*v.x + v.y*v.y + v.z*v.z + v.w*v.w;
  #pragma unroll
  for (int off = 32; off; off >>= 1) s += __shfl_down(s, off);
  if (lane == 0) {
    if (row < MDIM) { xx[r] = s; atomicAdd(Sxx, s); }
    else            { yy[r] = s; }
  }
}

// ---------- sx[k] = sum_i x[i,k] ----------
__global__ void sx_kernel(const float* __restrict__ x, float* __restrict__ sx) {
  int tx = threadIdx.x;
  int r0 = blockIdx.x * 16;
  float s = 0.f;
  #pragma unroll
  for (int r = 0; r < 16; ++r) s += x[(size_t)(r0 + r) * DDIM + tx];
  atomicAdd(&sx[tx], s);
}

// ---------- colM[j] = Sxx + MDIM*yy[j] - 2*dot(sx, y_j) ----------
__global__ void colM_kernel(const float* __restrict__ y, const float* __restrict__ sx,
                            const float* __restrict__ yy, const float* __restrict__ Sxx,
                            float* __restrict__ colM) {
  int wid = threadIdx.x >> 6, lane = threadIdx.x & 63;
  int j = blockIdx.x * 4 + wid;
  const float4* py = (const float4*)(y + (size_t)j * DDIM);
  const float4* ps = (const float4*)sx;
  float4 a = py[lane], b = ps[lane];
  float s = a.x*b.x + a.y*b.y + a.z*b.z + a.w*b.w;
  #pragma unroll
  for (int off = 32; off; off >>= 1) s += __shfl_down(s, off);
  if (lane == 0) colM[j] = *Sxx + (float)MDIM * yy[j] - 2.f * s;
}

// ---------- split x,y into bf16 hi/lo pairs ----------
__global__ void split_kernel(const float* __restrict__ x, const float* __restrict__ y,
                             ushort* __restrict__ xh, ushort* __restrict__ xl,
                             ushort* __restrict__ yh, ushort* __restrict__ yl) {
  int g = blockIdx.x * 256 + threadIdx.x;
  int e; const float4* src; ushort* dh; ushort* dl;
  if (g < 262144) { e = g;          src = (const float4*)x; dh = xh; dl = xl; }
  else            { e = g - 262144; src = (const float4*)y; dh = yh; dl = yl; }
  float4 v = src[e];
  float f[4] = {v.x, v.y, v.z, v.w};
  ushort hs[4], ls[4];
  #pragma unroll
  for (int i = 0; i < 4; ++i) {
    unsigned u = __float_as_uint(f[i]);
    unsigned hr = (u + 0x7FFFu + ((u >> 16) & 1u)) >> 16;
    hs[i] = (ushort)hr;
    float hf = __uint_as_float(hr << 16);
    float lo = f[i] - hf;
    unsigned ul = __float_as_uint(lo);
    unsigned lr = (ul + 0x7FFFu + ((ul >> 16) & 1u)) >> 16;
    ls[i] = (ushort)lr;
  }
  *(ushort4*)(dh + (size_t)e * 4) = make_ushort4(hs[0], hs[1], hs[2], hs[3]);
  *(ushort4*)(dl + (size_t)e * 4) = make_ushort4(ls[0], ls[1], ls[2], ls[3]);
}

// ---------- MFMA GEMM: D16 = round(65536 * (xh.yh + xh.yl + xl.yh)), plus maxdot ----------
#define GPAD 56
__global__ __launch_bounds__(256)
void gemm_mfma_kernel(const ushort* __restrict__ xh, const ushort* __restrict__ xl,
                      const ushort* __restrict__ yh, const ushort* __restrict__ yl,
                      short* __restrict__ D16, float* __restrict__ maxdot) {
  __shared__ ushort As[2][128][GPAD];
  __shared__ ushort Bs[2][128][GPAD];
  int tid = threadIdx.x;
  int lane = tid & 63, wid = tid >> 6;
  int bm = blockIdx.x & 31, bn = blockIdx.x >> 5;
  int wrow = (wid >> 1) * 64, wcol = (wid & 1) * 64;
  f32x4 acc[4][4] = {};

  int c0 = tid, c1 = tid + 256;
  int r0 = c0 >> 2, k80 = (c0 & 3) * 8;
  int r1 = c1 >> 2, k81 = (c1 & 3) * 8;
  const size_t arow0 = (size_t)(bm * 128 + r0) * DDIM;
  const size_t arow1 = (size_t)(bm * 128 + r1) * DDIM;
  const size_t brow0 = (size_t)(bn * 128 + r0) * DDIM;
  const size_t brow1 = (size_t)(bn * 128 + r1) * DDIM;

  for (int k0 = 0; k0 < DDIM; k0 += 32) {
    *(uint4*)&As[0][r0][k80] = *(const uint4*)(xh + arow0 + k0 + k80);
    *(uint4*)&As[0][r1][k81] = *(const uint4*)(xh + arow1 + k0 + k81);
    *(uint4*)&As[1][r0][k80] = *(const uint4*)(xl + arow0 + k0 + k80);
    *(uint4*)&As[1][r1][k81] = *(const uint4*)(xl + arow1 + k0 + k81);
    *(uint4*)&Bs[0][r0][k80] = *(const uint4*)(yh + brow0 + k0 + k80);
    *(uint4*)&Bs[0][r1][k81] = *(const uint4*)(yh + brow1 + k0 + k81);
    *(uint4*)&Bs[1][r0][k80] = *(const uint4*)(yl + brow0 + k0 + k80);
    *(uint4*)&Bs[1][r1][k81] = *(const uint4*)(yl + brow1 + k0 + k81);
    __syncthreads();
    int fr = lane & 15, kg = lane >> 4;
    bf16x8 ah[4], al[4], bh[4], bl[4];
    #pragma unroll
    for (int i = 0; i < 4; ++i) {
      ah[i] = *(const bf16x8*)&As[0][wrow + i * 16 + fr][kg * 8];
      al[i] = *(const bf16x8*)&As[1][wrow + i * 16 + fr][kg * 8];
      bh[i] = *(const bf16x8*)&Bs[0][wcol + i * 16 + fr][kg * 8];
      bl[i] = *(const bf16x8*)&Bs[1][wcol + i * 16 + fr][kg * 8];
    }
    #pragma unroll
    for (int i = 0; i < 4; ++i)
      #pragma unroll
      for (int j = 0; j < 4; ++j) {
        acc[i][j] = __builtin_amdgcn_mfma_f32_16x16x32_bf16(ah[i], bh[j], acc[i][j], 0, 0, 0);
        acc[i][j] = __builtin_amdgcn_mfma_f32_16x16x32_bf16(ah[i], bl[j], acc[i][j], 0, 0, 0);
        acc[i][j] = __builtin_amdgcn_mfma_f32_16x16x32_bf16(al[i], bh[j], acc[i][j], 0, 0, 0);
      }
    __syncthreads();
  }
  float tmax = -1.f;
  #pragma unroll
  for (int i = 0; i < 4; ++i) {
    #pragma unroll
    for (int j = 0; j < 4; ++j) {
      int col = bn * 128 + wcol + j * 16 + (lane & 15);
      #pragma unroll
      for (int r = 0; r < 4; ++r) {
        float d = acc[i][j][r];
        tmax = fmaxf(tmax, d);
        int q = __float2int_rn(fminf(fmaxf(d * 65536.f, -32767.f), 32767.f));
        int row = bm * 128 + wrow + i * 16 + (lane >> 4) * 4 + r;
        D16[(size_t)row * NDIM + col] = (short)q;
      }
    }
  }
  __shared__ float sm[4];
  #pragma unroll
  for (int off = 32; off; off >>= 1) tmax = fmaxf(tmax, __shfl_down(tmax, off));
  if (lane == 0) sm[wid] = tmax;
  __syncthreads();
  if (tid == 0) {
    float m = fmaxf(fmaxf(sm[0], sm[1]), fmaxf(sm[2], sm[3]));
    atomicMax((int*)maxdot, __float_as_int(fmaxf(m, 0.f)));
  }
}

// ---------- split-ownership solver, flag-based bipartite sync (no grid barrier) ----------
// blocks 0..127  (rowside): own 32 rows,  iters t=1..29, publish phi_{t+1}, phimax, rowFlag[t+1]
// blocks 128..255 (colside): own 32 cols, iters t=1..30, publish psi_{t+1}, psimax, colFlag[t+1]
__global__ __launch_bounds__(1024, 4)
void solve_kernel(const short* __restrict__ D16,
                  float* __restrict__ phi_pub, float* __restrict__ psi_pub,
                  const float* __restrict__ maxdot,
                  unsigned* rowMaxU, unsigned* colMaxU,
                  unsigned* rowFlag, unsigned* colFlag,
                  const float* __restrict__ colM,
                  float* lossacc, unsigned* lossdone,
                  float* __restrict__ out) {
  __shared__ float vec_lds[4096];
  __shared__ float red[32][33];
  __shared__ float own[32];
  __shared__ float sMax;
  int tid = threadIdx.x;
  int blk = blockIdx.x;
  bool rowside = blk < 128;
  int lloc = tid & 31;
  int chunk = tid >> 5;
  int obase = (rowside ? blk : (blk - 128)) * 32;
  float md = maxdot[0];

  unsigned* partnerFlag = rowside ? colFlag : rowFlag;
  unsigned* partnerMaxU = rowside ? colMaxU : rowMaxU;
  unsigned* myFlag      = rowside ? rowFlag : colFlag;
  unsigned* myMaxU      = rowside ? rowMaxU : colMaxU;
  const float* partnerPub = rowside ? psi_pub : phi_pub;
  float*       myPub      = rowside ? phi_pub : psi_pub;

  // one-time: 128 D16 entries per thread into 32 int2
  int2 d[32];
  if (rowside) {
    const short* src = D16 + (size_t)(obase + lloc) * NDIM + chunk * 128;
    #pragma unroll
    for (int g = 0; g < 32; ++g) d[g] = *(const int2*)(src + 4 * g);
  } else {
    int j = obase + lloc;
    #pragma unroll
    for (int g = 0; g < 32; ++g) {
      int rr = chunk * 128 + 4 * g;
      unsigned s0 = (unsigned short)(unsigned)D16[(size_t)(rr + 0) * NDIM + j];
      unsigned s1 = (unsigned short)(unsigned)D16[(size_t)(rr + 1) * NDIM + j];
      unsigned s2 = (unsigned short)(unsigned)D16[(size_t)(rr + 2) * NDIM + j];
      unsigned s3 = (unsigned short)(unsigned)D16[(size_t)(rr + 3) * NDIM + j];
      d[g].x = (int)(s0 | (s1 << 16));
      d[g].y = (int)(s2 | (s3 << 16));
    }
  }
  if (tid < 32) own[tid] = -6.f;

  int tEnd = rowside ? (N_ITER - 1) : N_ITER;
  for (int t = 1; t <= tEnd; ++t) {
    float sD  = (float)((double)t * (TWO_KAPPA / 65536.0));
    float tCL = (float)((double)t * CLCONST);
    float s2k = (float)((double)t * TWO_KAPPA);
    float tLmax = fmaf(s2k, md, tCL);

    float partnerMax;
    if (t == 1) partnerMax = -6.f;
    else {
      if (tid == 0) {
        while (AL_RLX(partnerFlag + t * 16) < 128u)
          __builtin_amdgcn_s_sleep(2);
        sMax = decf(AL_RLX(partnerMaxU + t * 16));
      }
      __syncthreads();
      partnerMax = sMax;
    }
    float Sh  = tLmax + partnerMax - 100.f;   // Sr (rowside) / Sc (colside)
    float Wsh = tCL - Sh;

    // stage partner vector (+ shift) into LDS
    {
      float4 v;
      if (t == 1) {
        float c = -6.f + Wsh;
        v = make_float4(c, c, c, c);
      } else {
        const float* src = partnerPub + (size_t)(t & 1) * 4096 + tid * 4;
        unsigned long long a = AL_RLX((const unsigned long long*)src);
        unsigned long long b = AL_RLX((const unsigned long long*)(src + 2));
        v.x = __uint_as_float((unsigned)a) + Wsh;
        v.y = __uint_as_float((unsigned)(a >> 32)) + Wsh;
        v.z = __uint_as_float((unsigned)b) + Wsh;
        v.w = __uint_as_float((unsigned)(b >> 32)) + Wsh;
      }
      *(float4*)&vec_lds[tid * 4] = v;
    }
    __syncthreads();

    // accumulate 128 entries: 1 exp2 + 1 fmaf + 1 add each
    float a0 = 0.f, a1 = 0.f, a2 = 0.f, a3 = 0.f;
    #pragma unroll
    for (int g = 0; g < 32; ++g) {
      float4 pv = *(const float4*)&vec_lds[chunk * 128 + 4 * g];
      int2 dv = d[g];
      float d0 = (float)((short)(dv.x & 0xFFFF));
      float d1 = (float)(dv.x >> 16);
      float d2 = (float)((short)(dv.y & 0xFFFF));
      float d3 = (float)(dv.y >> 16);
      a0 += exp2f(fmaf(d0, sD, pv.x));
      a1 += exp2f(fmaf(d1, sD, pv.y));
      a2 += exp2f(fmaf(d2, sD, pv.z));
      a3 += exp2f(fmaf(d3, sD, pv.w));
    }
    red[lloc][chunk] = (a0 + a1) + (a2 + a3);
    __syncthreads();

    if (tid < 32) {
      float tot = 0.f;
      #pragma unroll
      for (int c = 0; c < 32; ++c) tot += red[tid][c];
      if (rowside || t < N_ITER) {
        float pn = 0.5f * (own[tid] - Sh - log2f(fmaxf(tot, 1e-30f)));
        own[tid] = pn;
        AS_RLX(myPub + (size_t)((t + 1) & 1) * 4096 + obase + tid, pn);
        float mx = pn;
        #pragma unroll
        for (int o = 16; o; o >>= 1) mx = fmaxf(mx, __shfl_down(mx, o));
        if (tid == 0) {
          AMAX_RLX(myMaxU + (t + 1) * 16, encf(mx));
          asm volatile("s_waitcnt vmcnt(0)" ::: "memory");
          AADD_RLX(myFlag + (t + 1) * 16, 1u);
        }
      } else {
        // colside, t == 30: colsum_j = 2^{psi30_j + Sc30} * tot
        float contrib = exp2f(log2f(fmaxf(tot, 1e-30f)) + own[tid] + Sh
                              + log2f(colM[obase + tid]));
        #pragma unroll
        for (int o = 16; o; o >>= 1) contrib += __shfl_down(contrib, o);
        if (tid == 0) {
          AADD_RLX(&lossacc[blk & 15], contrib);
          asm volatile("s_waitcnt vmcnt(0)" ::: "memory");
          AADD_RLX(lossdone, 1u);
          if (blk == 128) {
            while (AL_RLX(lossdone) < 128u) __builtin_amdgcn_s_sleep(2);
            float tot2 = 0.f;
            #pragma unroll
            for (int s = 0; s < 16; ++s) tot2 += AL_RLX(&lossacc[s]);
            out[0] = tot2 * (1.f / ((float)MDIM * (float)MDIM));
          }
        }
      }
    }
  }
}

extern "C" void kernel_launch(void* const* d_in, const int* in_sizes, int n_in,
                              void* d_out, int out_size, void* d_ws, size_t ws_size,
                              hipStream_t stream) {
  const float* x = (const float*)d_in[0];
  const float* y = (const float*)d_in[1];
  float* out = (float*)d_out;

  char* ws = (char*)d_ws;
  size_t off = 0;
  auto alloc = [&](size_t bytes) -> void* {
    void* p = ws + off;
    off += (bytes + 255) & ~(size_t)255;
    return p;
  };
  short*    D16     = (short*)alloc((size_t)MDIM * NDIM * 2);      // 32 MB
  ushort*   xh      = (ushort*)alloc((size_t)MDIM * DDIM * 2);
  ushort*   xl      = (ushort*)alloc((size_t)MDIM * DDIM * 2);
  ushort*   yh      = (ushort*)alloc((size_t)NDIM * DDIM * 2);
  ushort*   yl      = (ushort*)alloc((size_t)NDIM * DDIM * 2);
  float*    xx      = (float*)alloc(MDIM * 4);
  float*    yy      = (float*)alloc(NDIM * 4);
  float*    sx      = (float*)alloc(DDIM * 4);
  float*    colM    = (float*)alloc(NDIM * 4);
  float*    Sxx     = (float*)alloc(4);
  float*    maxd    = (float*)alloc(4);
  float*    phi_pub = (float*)alloc(2 * MDIM * 4);
  float*    psi_pub = (float*)alloc(2 * NDIM * 4);
  unsigned* rowMaxU = (unsigned*)alloc(32 * 16 * 4);
  unsigned* colMaxU = (unsigned*)alloc(32 * 16 * 4);
  unsigned* rowFlag = (unsigned*)alloc(32 * 16 * 4);
  unsigned* colFlag = (unsigned*)alloc(32 * 16 * 4);
  float*    lossacc = (float*)alloc(16 * 4);
  unsigned* lossdone= (unsigned*)alloc(16 * 4);

  hipMemsetAsync(Sxx, 0, 4, stream);
  hipMemsetAsync(maxd, 0, 4, stream);
  hipMemsetAsync(sx, 0, DDIM * 4, stream);
  hipMemsetAsync(rowMaxU, 0, 32 * 16 * 4, stream);
  hipMemsetAsync(colMaxU, 0, 32 * 16 * 4, stream);
  hipMemsetAsync(rowFlag, 0, 32 * 16 * 4, stream);
  hipMemsetAsync(colFlag, 0, 32 * 16 * 4, stream);
  hipMemsetAsync(lossacc, 0, 16 * 4, stream);
  hipMemsetAsync(lossdone, 0, 16 * 4, stream);

  norms_kernel<<<2048, 256, 0, stream>>>(x, y, xx, yy, Sxx);
  sx_kernel<<<256, 256, 0, stream>>>(x, sx);
  colM_kernel<<<1024, 256, 0, stream>>>(y, sx, yy, Sxx, colM);
  split_kernel<<<2048, 256, 0, stream>>>(x, y, xh, xl, yh, yl);
  gemm_mfma_kernel<<<1024, 256, 0, stream>>>(xh, xl, yh, yl, D16, maxd);

  void* kargs[] = {(void*)&D16, (void*)&phi_pub, (void*)&psi_pub,
                   (void*)&maxd, (void*)&rowMaxU, (void*)&colMaxU,
                   (void*)&rowFlag, (void*)&colFlag,
                   (void*)&colM, (void*)&lossacc, (void*)&lossdone,
                   (void*)&out};
  hipLaunchCooperativeKernel((void*)solve_kernel, dim3(256), dim3(1024),
                             kargs, 0, stream);
}

// Round 9
// 989.408 us; speedup vs baseline: 1.0378x; 1.0378x over previous
//
#include <hip/hip_runtime.h>
#include <math.h>

#define MDIM 4096
#define NDIM 4096
#define DDIM 256
#define N_ITER 30

#define TWO_KAPPA 14.426950408889634
#define CLCONST  (-12.0 - TWO_KAPPA)

typedef __attribute__((ext_vector_type(8))) short bf16x8;
typedef __attribute__((ext_vector_type(4))) float f32x4;

__device__ __forceinline__ unsigned encf(float f) {
  unsigned u = __float_as_uint(f);
  return (u & 0x80000000u) ? ~u : (u | 0x80000000u);
}
__device__ __forceinline__ float decf(unsigned u) {
  return __uint_as_float((u & 0x80000000u) ? (u ^ 0x80000000u) : ~u);
}

#define AL_RLX(p)      __hip_atomic_load((p), __ATOMIC_RELAXED, __HIP_MEMORY_SCOPE_AGENT)
#define AS_RLX(p, v)   __hip_atomic_store((p), (v), __ATOMIC_RELAXED, __HIP_MEMORY_SCOPE_AGENT)
#define AADD_RLX(p, v) __hip_atomic_fetch_add((p), (v), __ATOMIC_RELAXED, __HIP_MEMORY_SCOPE_AGENT)
#define AMAX_RLX(p, v) __hip_atomic_fetch_max((p), (v), __ATOMIC_RELAXED, __HIP_MEMORY_SCOPE_AGENT)

// ---------- norms: xx[i], yy[j], Sxx ----------
__global__ void norms_kernel(const float* __restrict__ x, const float* __restrict__ y,
                             float* __restrict__ xx, float* __restrict__ yy,
                             float* __restrict__ Sxx) {
  int wid = threadIdx.x >> 6, lane = threadIdx.x & 63;
  int row = blockIdx.x * 4 + wid;
  const float* src = (row < MDIM) ? x : y;
  int r = (row < MDIM) ? row : row - MDIM;
  const float4* p = (const float4*)(src + (size_t)r * DDIM);
  float4 v = p[lane];
  float s = v.x*v.x + v.y*v.y + v.z*v.z + v.w*v.w;
  #pragma unroll
  for (int off = 32; off; off >>= 1) s += __shfl_down(s, off);
  if (lane == 0) {
    if (row < MDIM) { xx[r] = s; atomicAdd(Sxx, s); }
    else            { yy[r] = s; }
  }
}

// ---------- sx[k] = sum_i x[i,k] ----------
__global__ void sx_kernel(const float* __restrict__ x, float* __restrict__ sx) {
  int tx = threadIdx.x;
  int r0 = blockIdx.x * 16;
  float s = 0.f;
  #pragma unroll
  for (int r = 0; r < 16; ++r) s += x[(size_t)(r0 + r) * DDIM + tx];
  atomicAdd(&sx[tx], s);
}

// ---------- colM[j] = Sxx + MDIM*yy[j] - 2*dot(sx, y_j) ----------
__global__ void colM_kernel(const float* __restrict__ y, const float* __restrict__ sx,
                            const float* __restrict__ yy, const float* __restrict__ Sxx,
                            float* __restrict__ colM) {
  int wid = threadIdx.x >> 6, lane = threadIdx.x & 63;
  int j = blockIdx.x * 4 + wid;
  const float4* py = (const float4*)(y + (size_t)j * DDIM);
  const float4* ps = (const float4*)sx;
  float4 a = py[lane], b = ps[lane];
  float s = a.x*b.x + a.y*b.y + a.z*b.z + a.w*b.w;
  #pragma unroll
  for (int off = 32; off; off >>= 1) s += __shfl_down(s, off);
  if (lane == 0) colM[j] = *Sxx + (float)MDIM * yy[j] - 2.f * s;
}

// ---------- split x,y into bf16 hi/lo pairs ----------
__global__ void split_kernel(const float* __restrict__ x, const float* __restrict__ y,
                             ushort* __restrict__ xh, ushort* __restrict__ xl,
                             ushort* __restrict__ yh, ushort* __restrict__ yl) {
  int g = blockIdx.x * 256 + threadIdx.x;
  int e; const float4* src; ushort* dh; ushort* dl;
  if (g < 262144) { e = g;          src = (const float4*)x; dh = xh; dl = xl; }
  else            { e = g - 262144; src = (const float4*)y; dh = yh; dl = yl; }
  float4 v = src[e];
  float f[4] = {v.x, v.y, v.z, v.w};
  ushort hs[4], ls[4];
  #pragma unroll
  for (int i = 0; i < 4; ++i) {
    unsigned u = __float_as_uint(f[i]);
    unsigned hr = (u + 0x7FFFu + ((u >> 16) & 1u)) >> 16;
    hs[i] = (ushort)hr;
    float hf = __uint_as_float(hr << 16);
    float lo = f[i] - hf;
    unsigned ul = __float_as_uint(lo);
    unsigned lr = (ul + 0x7FFFu + ((ul >> 16) & 1u)) >> 16;
    ls[i] = (ushort)lr;
  }
  *(ushort4*)(dh + (size_t)e * 4) = make_ushort4(hs[0], hs[1], hs[2], hs[3]);
  *(ushort4*)(dl + (size_t)e * 4) = make_ushort4(ls[0], ls[1], ls[2], ls[3]);
}

// ---------- MFMA GEMM: D16 = round(65536 * (xh.yh + xh.yl + xl.yh)), plus maxdot ----------
#define GPAD 56
__global__ __launch_bounds__(256)
void gemm_mfma_kernel(const ushort* __restrict__ xh, const ushort* __restrict__ xl,
                      const ushort* __restrict__ yh, const ushort* __restrict__ yl,
                      short* __restrict__ D16, float* __restrict__ maxdot) {
  __shared__ ushort As[2][128][GPAD];
  __shared__ ushort Bs[2][128][GPAD];
  int tid = threadIdx.x;
  int lane = tid & 63, wid = tid >> 6;
  int bm = blockIdx.x & 31, bn = blockIdx.x >> 5;
  int wrow = (wid >> 1) * 64, wcol = (wid & 1) * 64;
  f32x4 acc[4][4] = {};

  int c0 = tid, c1 = tid + 256;
  int r0 = c0 >> 2, k80 = (c0 & 3) * 8;
  int r1 = c1 >> 2, k81 = (c1 & 3) * 8;
  const size_t arow0 = (size_t)(bm * 128 + r0) * DDIM;
  const size_t arow1 = (size_t)(bm * 128 + r1) * DDIM;
  const size_t brow0 = (size_t)(bn * 128 + r0) * DDIM;
  const size_t brow1 = (size_t)(bn * 128 + r1) * DDIM;

  for (int k0 = 0; k0 < DDIM; k0 += 32) {
    *(uint4*)&As[0][r0][k80] = *(const uint4*)(xh + arow0 + k0 + k80);
    *(uint4*)&As[0][r1][k81] = *(const uint4*)(xh + arow1 + k0 + k81);
    *(uint4*)&As[1][r0][k80] = *(const uint4*)(xl + arow0 + k0 + k80);
    *(uint4*)&As[1][r1][k81] = *(const uint4*)(xl + arow1 + k0 + k81);
    *(uint4*)&Bs[0][r0][k80] = *(const uint4*)(yh + brow0 + k0 + k80);
    *(uint4*)&Bs[0][r1][k81] = *(const uint4*)(yh + brow1 + k0 + k81);
    *(uint4*)&Bs[1][r0][k80] = *(const uint4*)(yl + brow0 + k0 + k80);
    *(uint4*)&Bs[1][r1][k81] = *(const uint4*)(yl + brow1 + k0 + k81);
    __syncthreads();
    int fr = lane & 15, kg = lane >> 4;
    bf16x8 ah[4], al[4], bh[4], bl[4];
    #pragma unroll
    for (int i = 0; i < 4; ++i) {
      ah[i] = *(const bf16x8*)&As[0][wrow + i * 16 + fr][kg * 8];
      al[i] = *(const bf16x8*)&As[1][wrow + i * 16 + fr][kg * 8];
      bh[i] = *(const bf16x8*)&Bs[0][wcol + i * 16 + fr][kg * 8];
      bl[i] = *(const bf16x8*)&Bs[1][wcol + i * 16 + fr][kg * 8];
    }
    #pragma unroll
    for (int i = 0; i < 4; ++i)
      #pragma unroll
      for (int j = 0; j < 4; ++j) {
        acc[i][j] = __builtin_amdgcn_mfma_f32_16x16x32_bf16(ah[i], bh[j], acc[i][j], 0, 0, 0);
        acc[i][j] = __builtin_amdgcn_mfma_f32_16x16x32_bf16(ah[i], bl[j], acc[i][j], 0, 0, 0);
        acc[i][j] = __builtin_amdgcn_mfma_f32_16x16x32_bf16(al[i], bh[j], acc[i][j], 0, 0, 0);
      }
    __syncthreads();
  }
  float tmax = -1.f;
  #pragma unroll
  for (int i = 0; i < 4; ++i) {
    #pragma unroll
    for (int j = 0; j < 4; ++j) {
      int col = bn * 128 + wcol + j * 16 + (lane & 15);
      #pragma unroll
      for (int r = 0; r < 4; ++r) {
        float d = acc[i][j][r];
        tmax = fmaxf(tmax, d);
        int q = __float2int_rn(fminf(fmaxf(d * 65536.f, -32767.f), 32767.f));
        int row = bm * 128 + wrow + i * 16 + (lane >> 4) * 4 + r;
        D16[(size_t)row * NDIM + col] = (short)q;
      }
    }
  }
  __shared__ float sm[4];
  #pragma unroll
  for (int off = 32; off; off >>= 1) tmax = fmaxf(tmax, __shfl_down(tmax, off));
  if (lane == 0) sm[wid] = tmax;
  __syncthreads();
  if (tid == 0) {
    float m = fmaxf(fmaxf(sm[0], sm[1]), fmaxf(sm[2], sm[3]));
    atomicMax((int*)maxdot, __float_as_int(fmaxf(m, 0.f)));
  }
}

// ---------- persistent solver: LDS-resident stripe, single exp2 per entry ----------
// 256 blocks, block b owns rows [16b,16b+16) for the E-pass and cols [16b,16b+16)
// for the column reduction. E_ij = 2^(tL + phi_i + psi_j - S). One colp matrix,
// relaxed-atomic flag protocol (validated r8).
__global__ __launch_bounds__(1024)
void solve_kernel(const short* __restrict__ D16,
                  float* __restrict__ colp,
                  float* __restrict__ psi_pub,
                  const float* __restrict__ maxdot,
                  unsigned* phimaxS, unsigned* psimaxS,
                  unsigned* flag1, unsigned* flag2,
                  const float* __restrict__ colM,
                  float* lossacc, unsigned* lossdone,
                  float* __restrict__ out) {
  __shared__ ushort stripeS[16 * 4096];   // 128 KB
  __shared__ float  vecS[4096];           // psi_t (raw)
  __shared__ float  redrow[16][16];
  __shared__ float  red2[16][16];
  __shared__ float  ownS[16];             // phi_t of owned rows
  __shared__ float  sS[2];
  int tid = threadIdx.x, lane = tid & 63, wid = tid >> 6;
  int b = blockIdx.x;
  float md = maxdot[0];

  // one-time: stripe -> LDS (coalesced 16B)
  {
    const uint4* src = (const uint4*)(D16 + (size_t)b * 16 * NDIM);
    uint4* dst = (uint4*)stripeS;
    #pragma unroll
    for (int k = 0; k < 8; ++k) dst[tid + 1024 * k] = src[tid + 1024 * k];
  }
  if (tid < 16) ownS[tid] = -6.f;
  __syncthreads();

  for (int t = 1; t <= N_ITER; ++t) {
    float sD  = (float)((double)t * (TWO_KAPPA / 65536.0));
    float tCL = (float)((double)t * CLCONST);
    float s2k = (float)((double)t * TWO_KAPPA);

    // ---- A: wait psi_t ready, gather maxes ----
    if (t > 1) {
      if (tid == 0) {
        while (AL_RLX(&flag2[(t - 1) * 16]) < 256u) __builtin_amdgcn_s_sleep(2);
        unsigned uf = 0, up = 0;
        #pragma unroll
        for (int s = 0; s < 16; ++s) {
          unsigned a = AL_RLX(&phimaxS[t * 16 + s]); uf = a > uf ? a : uf;
          unsigned c = AL_RLX(&psimaxS[t * 16 + s]); up = c > up ? c : up;
        }
        sS[0] = decf(uf); sS[1] = decf(up);
      }
      __syncthreads();
    }
    float fm = (t == 1) ? -6.f : sS[0];
    float pm = (t == 1) ? -6.f : sS[1];
    float tLmax = fmaf(s2k, md, tCL);
    float S  = tLmax + fm + pm - 100.f;
    float WS = tCL - S;

    // ---- B: stage psi_t ----
    if (t == 1) {
      *(float4*)&vecS[4 * tid] = make_float4(-6.f, -6.f, -6.f, -6.f);
    } else {
      const unsigned long long* sp =
          (const unsigned long long*)(psi_pub + (size_t)(t & 1) * 4096 + 4 * tid);
      unsigned long long a = AL_RLX(sp), c = AL_RLX(sp + 1);
      float4 v;
      v.x = __uint_as_float((unsigned)a); v.y = __uint_as_float((unsigned)(a >> 32));
      v.z = __uint_as_float((unsigned)c); v.w = __uint_as_float((unsigned)(c >> 32));
      *(float4*)&vecS[4 * tid] = v;
    }
    __syncthreads();

    // ---- C: E-pass over 16 rows x 4 cols per thread ----
    float4 psi4 = *(const float4*)&vecS[4 * tid];
    float P0 = psi4.x + WS, P1 = psi4.y + WS, P2 = psi4.z + WS, P3 = psi4.w + WS;
    float c0 = 0.f, c1 = 0.f, c2 = 0.f, c3 = 0.f;
    float rs[16];
    #pragma unroll
    for (int r = 0; r < 16; ++r) {
      float phr = ownS[r];
      int2 dv = *(const int2*)(stripeS + r * 4096 + 4 * tid);
      float d0 = (float)((short)(dv.x & 0xFFFF));
      float d1 = (float)(dv.x >> 16);
      float d2 = (float)((short)(dv.y & 0xFFFF));
      float d3 = (float)(dv.y >> 16);
      float e0 = exp2f(fmaf(d0, sD, P0 + phr));
      float e1 = exp2f(fmaf(d1, sD, P1 + phr));
      float e2 = exp2f(fmaf(d2, sD, P2 + phr));
      float e3 = exp2f(fmaf(d3, sD, P3 + phr));
      c0 += e0; c1 += e1; c2 += e2; c3 += e3;
      rs[r] = (e0 + e1) + (e2 + e3);
    }
    // publish col partials (agent-visible atomic stores)
    {
      unsigned long long u0 = ((unsigned long long)__float_as_uint(c1) << 32) | __float_as_uint(c0);
      unsigned long long u1 = ((unsigned long long)__float_as_uint(c3) << 32) | __float_as_uint(c2);
      unsigned long long* cp = (unsigned long long*)(colp + (size_t)b * 4096 + 4 * tid);
      AS_RLX(cp, u0); AS_RLX(cp + 1, u1);
    }
    // ---- D: row sums -> phi_{t+1} (block-local) ----
    if (t < N_ITER) {
      #pragma unroll
      for (int r = 0; r < 16; ++r) {
        float v = rs[r];
        #pragma unroll
        for (int o = 32; o; o >>= 1) v += __shfl_down(v, o);
        if (lane == 0) redrow[r][wid] = v;
      }
      __syncthreads();
      if (tid < 16) {
        float s = 0.f;
        #pragma unroll
        for (int w = 0; w < 16; ++w) s += redrow[tid][w];
        float pn = ownS[tid] - 0.5f * (S + log2f(fmaxf(s, 1e-30f)));
        ownS[tid] = pn;
        float mx = pn;
        #pragma unroll
        for (int o = 8; o; o >>= 1) mx = fmaxf(mx, __shfl_down(mx, o));
        if (tid == 0) AMAX_RLX(&phimaxS[(t + 1) * 16 + (b & 15)], encf(mx));
      }
    }
    asm volatile("s_waitcnt vmcnt(0)" ::: "memory");   // every wave drains its stores
    __syncthreads();
    if (tid == 0) {
      AADD_RLX(&flag1[t * 16], 1u);
      while (AL_RLX(&flag1[t * 16]) < 256u) __builtin_amdgcn_s_sleep(2);
    }
    __syncthreads();

    // ---- G: reduce owned cols [16b,16b+16) over 256 blocks ----
    {
      int k  = tid >> 2;
      int cq = (tid & 3) * 4;
      const unsigned long long* rp =
          (const unsigned long long*)(colp + (size_t)k * 4096 + 16 * b + cq);
      unsigned long long a = AL_RLX(rp), c = AL_RLX(rp + 1);
      float f0 = __uint_as_float((unsigned)a), f1 = __uint_as_float((unsigned)(a >> 32));
      float f2 = __uint_as_float((unsigned)c), f3 = __uint_as_float((unsigned)(c >> 32));
      #pragma unroll
      for (int o = 4; o < 64; o <<= 1) {
        f0 += __shfl_down(f0, o); f1 += __shfl_down(f1, o);
        f2 += __shfl_down(f2, o); f3 += __shfl_down(f3, o);
      }
      if (lane < 4) *(float4*)&red2[wid][lane * 4] = make_float4(f0, f1, f2, f3);
    }
    __syncthreads();
    if (tid < 16) {
      float tot = 0.f;
      #pragma unroll
      for (int w = 0; w < 16; ++w) tot += red2[w][tid];
      int jj = 16 * b + tid;
      if (t < N_ITER) {
        float pn = vecS[jj] - 0.5f * (S + log2f(fmaxf(tot, 1e-30f)));
        AS_RLX(&psi_pub[(size_t)((t + 1) & 1) * 4096 + jj], pn);
        float mx = pn;
        #pragma unroll
        for (int o = 8; o; o >>= 1) mx = fmaxf(mx, __shfl_down(mx, o));
        if (tid == 0) {
          AMAX_RLX(&psimaxS[(t + 1) * 16 + (b & 15)], encf(mx));
          asm volatile("s_waitcnt vmcnt(0)" ::: "memory");
          AADD_RLX(&flag2[t * 16], 1u);
        }
      } else {
        // t == 30: loss = sum_j 2^S * colsumE_j * colM_j / 2^24
        float term = (tot * 9.094947017729282e-13f) * colM[jj];   // 2^-40 prescale
        #pragma unroll
        for (int o = 8; o; o >>= 1) term += __shfl_down(term, o);
        if (tid == 0) {
          AADD_RLX(&lossacc[b & 15], term);
          asm volatile("s_waitcnt vmcnt(0)" ::: "memory");
          AADD_RLX(lossdone, 1u);
          if (b == 0) {
            while (AL_RLX(lossdone) < 256u) __builtin_amdgcn_s_sleep(2);
            float tt = 0.f;
            #pragma unroll
            for (int s = 0; s < 16; ++s) tt += AL_RLX(&lossacc[s]);
            out[0] = exp2f(log2f(tt) + S + 16.f);   // +40 (prescale) - 24 (1/m^2)
          }
        }
      }
    }
  }
}

extern "C" void kernel_launch(void* const* d_in, const int* in_sizes, int n_in,
                              void* d_out, int out_size, void* d_ws, size_t ws_size,
                              hipStream_t stream) {
  const float* x = (const float*)d_in[0];
  const float* y = (const float*)d_in[1];
  float* out = (float*)d_out;

  char* ws = (char*)d_ws;
  size_t off = 0;
  auto alloc = [&](size_t bytes) -> void* {
    void* p = ws + off;
    off += (bytes + 255) & ~(size_t)255;
    return p;
  };
  short*    D16     = (short*)alloc((size_t)MDIM * NDIM * 2);      // 32 MB
  float*    colp    = (float*)alloc((size_t)256 * NDIM * 4);       // 4 MB
  ushort*   xh      = (ushort*)alloc((size_t)MDIM * DDIM * 2);
  ushort*   xl      = (ushort*)alloc((size_t)MDIM * DDIM * 2);
  ushort*   yh      = (ushort*)alloc((size_t)NDIM * DDIM * 2);
  ushort*   yl      = (ushort*)alloc((size_t)NDIM * DDIM * 2);
  float*    xx      = (float*)alloc(MDIM * 4);
  float*    yy      = (float*)alloc(NDIM * 4);
  float*    sx      = (float*)alloc(DDIM * 4);
  float*    colM    = (float*)alloc(NDIM * 4);
  float*    Sxx     = (float*)alloc(4);
  float*    maxd    = (float*)alloc(4);
  float*    psi_pub = (float*)alloc(2 * NDIM * 4);
  unsigned* phimaxS = (unsigned*)alloc(32 * 16 * 4);
  unsigned* psimaxS = (unsigned*)alloc(32 * 16 * 4);
  unsigned* flag1   = (unsigned*)alloc(32 * 16 * 4);
  unsigned* flag2   = (unsigned*)alloc(32 * 16 * 4);
  float*    lossacc = (float*)alloc(16 * 4);
  unsigned* lossdone= (unsigned*)alloc(16 * 4);

  hipMemsetAsync(Sxx, 0, 4, stream);
  hipMemsetAsync(maxd, 0, 4, stream);
  hipMemsetAsync(sx, 0, DDIM * 4, stream);
  hipMemsetAsync(phimaxS, 0, 32 * 16 * 4, stream);
  hipMemsetAsync(psimaxS, 0, 32 * 16 * 4, stream);
  hipMemsetAsync(flag1, 0, 32 * 16 * 4, stream);
  hipMemsetAsync(flag2, 0, 32 * 16 * 4, stream);
  hipMemsetAsync(lossacc, 0, 16 * 4, stream);
  hipMemsetAsync(lossdone, 0, 16 * 4, stream);

  norms_kernel<<<2048, 256, 0, stream>>>(x, y, xx, yy, Sxx);
  sx_kernel<<<256, 256, 0, stream>>>(x, sx);
  colM_kernel<<<1024, 256, 0, stream>>>(y, sx, yy, Sxx, colM);
  split_kernel<<<2048, 256, 0, stream>>>(x, y, xh, xl, yh, yl);
  gemm_mfma_kernel<<<1024, 256, 0, stream>>>(xh, xl, yh, yl, D16, maxd);

  void* kargs[] = {(void*)&D16, (void*)&colp, (void*)&psi_pub,
                   (void*)&maxd, (void*)&phimaxS, (void*)&psimaxS,
                   (void*)&flag1, (void*)&flag2,
                   (void*)&colM, (void*)&lossacc, (void*)&lossdone,
                   (void*)&out};
  hipLaunchCooperativeKernel((void*)solve_kernel, dim3(256), dim3(1024),
                             kargs, 0, stream);
}